// Round 5
// baseline (159.710 us; speedup 1.0000x reference)
//
#include <hip/hip_runtime.h>
#include <math.h>

#define BATCH  512
#define NROWS  256
#define NVECS  8
#define VSIZE  128
#define DIM    1024   // NVECS*VSIZE
#define NCOMBO 256

// ---------------------------------------------------------------------------
// R5: two-kernel split. R1/R2/R4 (schedule, occupancy, instruction-count)
// were all null; corrected pipe model says the fused kernel is sum-bound:
// per-CU LDS pipe ~15us + VALU ~7us + stores ~20us + bubbles ~= 63us.
// The fix is structural: don't make the store stream share a CU-serialized
// dependency chain with the DS/butterfly work.
//
// Kernel A (cos-sims, ~6-8us): grid 64x32, 256 thr. NO LDS, no barriers.
//   Each wave: 2 Q rows in regs, loops 8 W rows straight from global
//   (1 MB W is L2-resident), 48 FMA + 3-var 3-step xor butterfly per row,
//   writes 8 inverse-normed cos-sims per (b,r) pair to cs[] in d_ws (4 MB).
// Kernel B (expand, ~20-24us): fill-shaped pure streaming. grid 2048, 256
//   thr, ~30 VGPR, zero LDS/cross-lane/barriers. Per wave-iteration: one
//   wave-uniform 32 B cs read (readfirstlane -> scalar path), ~25 VALU,
//   one contiguous 1 KB float4 store; 16 iters = contiguous 16 KB per wave.
//   The 512 MiB harness fill proves this structure runs at 6.6 TB/s.
// ---------------------------------------------------------------------------

__global__ __launch_bounds__(256) void cos_kernel(
    const float* __restrict__ q, const float* __restrict__ w,
    float* __restrict__ cs) {
  const int t    = threadIdx.x;
  const int wv   = t >> 6, lane = t & 63;
  const int bs   = blockIdx.x * 8, rs = blockIdx.y * 8;
  const int c    = lane & 7, n = lane >> 3;
  const int koff = lane * 16;              // == n*VSIZE + c*16
  const int b0   = bs + 2 * wv;

  // Q rows -> registers; per-chunk inverse norms via 3-step group butterfly.
  float4 qa[4], qb[4];
  float qs0 = 0.f, qs1 = 0.f;
  {
    const float* Q0 = q + (size_t)b0 * DIM + koff;
    #pragma unroll
    for (int j = 0; j < 4; ++j) {
      qa[j] = *(const float4*)(Q0 + 4 * j);
      qb[j] = *(const float4*)(Q0 + DIM + 4 * j);
      qs0 = fmaf(qa[j].x, qa[j].x, qs0); qs0 = fmaf(qa[j].y, qa[j].y, qs0);
      qs0 = fmaf(qa[j].z, qa[j].z, qs0); qs0 = fmaf(qa[j].w, qa[j].w, qs0);
      qs1 = fmaf(qb[j].x, qb[j].x, qs1); qs1 = fmaf(qb[j].y, qb[j].y, qs1);
      qs1 = fmaf(qb[j].z, qb[j].z, qs1); qs1 = fmaf(qb[j].w, qb[j].w, qs1);
    }
  }
  #pragma unroll
  for (int m = 1; m <= 4; m <<= 1) {
    qs0 += __shfl_xor(qs0, m, 64);
    qs1 += __shfl_xor(qs1, m, 64);
  }
  const float iq0 = 1.0f / fmaxf(sqrtf(qs0), 1e-8f);
  const float iq1 = 1.0f / fmaxf(sqrtf(qs1), 1e-8f);

  // 8 W rows straight from global (L2-hot), dots + w-sub-norms in-register.
  #pragma unroll 2
  for (int r = 0; r < 8; ++r) {
    const float* Wr = w + (size_t)(rs + r) * DIM + koff;
    float s0 = 0.f, s1 = 0.f, wss = 0.f;
    #pragma unroll
    for (int j = 0; j < 4; ++j) {
      float4 w4 = *(const float4*)(Wr + 4 * j);
      s0 = fmaf(qa[j].x, w4.x, s0); s0 = fmaf(qa[j].y, w4.y, s0);
      s0 = fmaf(qa[j].z, w4.z, s0); s0 = fmaf(qa[j].w, w4.w, s0);
      s1 = fmaf(qb[j].x, w4.x, s1); s1 = fmaf(qb[j].y, w4.y, s1);
      s1 = fmaf(qb[j].z, w4.z, s1); s1 = fmaf(qb[j].w, w4.w, s1);
      wss = fmaf(w4.x, w4.x, wss); wss = fmaf(w4.y, w4.y, wss);
      wss = fmaf(w4.z, w4.z, wss); wss = fmaf(w4.w, w4.w, wss);
    }
    #pragma unroll
    for (int m = 1; m <= 4; m <<= 1) {
      s0  += __shfl_xor(s0, m, 64);
      s1  += __shfl_xor(s1, m, 64);
      wss += __shfl_xor(wss, m, 64);
    }
    const float iw  = 1.0f / fmaxf(sqrtf(wss), 1e-8f);
    const float cs0 = fmaxf(s0 * iq0 * iw, 0.f);
    const float cs1 = fmaxf(s1 * iq1 * iw, 0.f);
    if (c < 2) {
      float csv = (c == 0) ? cs0 : cs1;
      cs[((size_t)(b0 + c) * NROWS + (rs + r)) * 8 + n] = csv;
    }
  }
}

__global__ __launch_bounds__(256) void expand_kernel(
    const float* __restrict__ cs, float* __restrict__ out) {
  const int t    = threadIdx.x;
  const int wv   = t >> 6, lane = t & 63;
  const bool m2 = lane & 1,  m3 = lane & 2,  m4 = lane & 4;
  const bool m5 = lane & 8,  m6 = lane & 16, m7 = lane & 32;
  const int wbase = (blockIdx.x * 4 + wv) * 16;   // pair index base
  float* outL = out + lane * 4;
  #pragma unroll 4
  for (int it = 0; it < 16; ++it) {
    // p is wave-uniform; readfirstlane tells the compiler so (scalar loads).
    const int p = __builtin_amdgcn_readfirstlane(wbase + it);
    const float* cp = cs + ((size_t)p << 3);
    float4 va = *(const float4*)(cp);       // cs[0..3]
    float4 vb = *(const float4*)(cp + 4);   // cs[4..7]
    float t2 = m2 ? 1.f - va.z : va.z;
    float t3 = m3 ? 1.f - va.w : va.w;
    float t4 = m4 ? 1.f - vb.x : vb.x;
    float t5 = m5 ? 1.f - vb.y : vb.y;
    float t6 = m6 ? 1.f - vb.z : vb.z;
    float t7 = m7 ? 1.f - vb.w : vb.w;
    float base = ((t2 * t3) * (t4 * t5)) * (t6 * t7);
    float c0 = va.x, c1 = va.y;
    float4 o;
    o.x = base * (c0 * c1);
    o.y = base * ((1.f - c0) * c1);
    o.z = base * (c0 * (1.f - c1));
    o.w = base * ((1.f - c0) * (1.f - c1));
    *(float4*)(outL + ((size_t)p << 8)) = o;   // p*256 floats, 1KB/wave
  }
}

// ---------------------------------------------------------------------------
// Fallback (known-good R1 fused kernel, 145us) if the workspace is too small.
// ---------------------------------------------------------------------------
__global__ __launch_bounds__(256) void fused_kernel(
    const float* __restrict__ q, const float* __restrict__ w,
    float* __restrict__ out) {
  __shared__ __align__(16) float Ws[8 * 1056];
  __shared__ __align__(16) float Cs[8 * 64];
  const int t    = threadIdx.x;
  const int wv   = t >> 6, lane = t & 63;
  const int bs   = blockIdx.x * 8, rs = blockIdx.y * 8;
  const int n    = lane >> 3, c = lane & 7;
  const int koff = n * VSIZE + c * 16;
  const int b0   = bs + 2 * wv;

  #pragma unroll
  for (int i = 0; i < 8; ++i) {
    int f = i * 256 + t;
    int g = f << 2;
    int row = g >> 10, e = g & 1023;
    float4 v = *(const float4*)(w + (size_t)(rs + row) * DIM + e);
    *(float4*)(Ws + row * 1056 + (e >> 7) * 132 + (e & 127)) = v;
  }

  float4 qa[4], qb[4];
  float qs0 = 0.f, qs1 = 0.f;
  {
    const float* Q0 = q + (size_t)b0 * DIM + koff;
    #pragma unroll
    for (int j = 0; j < 4; ++j) {
      qa[j] = *(const float4*)(Q0 + 4 * j);
      qb[j] = *(const float4*)(Q0 + DIM + 4 * j);
      qs0 = fmaf(qa[j].x, qa[j].x, qs0); qs0 = fmaf(qa[j].y, qa[j].y, qs0);
      qs0 = fmaf(qa[j].z, qa[j].z, qs0); qs0 = fmaf(qa[j].w, qa[j].w, qs0);
      qs1 = fmaf(qb[j].x, qb[j].x, qs1); qs1 = fmaf(qb[j].y, qb[j].y, qs1);
      qs1 = fmaf(qb[j].z, qb[j].z, qs1); qs1 = fmaf(qb[j].w, qb[j].w, qs1);
    }
  }
  #pragma unroll
  for (int m = 1; m <= 4; m <<= 1) {
    qs0 += __shfl_xor(qs0, m, 64);
    qs1 += __shfl_xor(qs1, m, 64);
  }
  const float iq0 = 1.0f / fmaxf(sqrtf(qs0), 1e-8f);
  const float iq1 = 1.0f / fmaxf(sqrtf(qs1), 1e-8f);

  __syncthreads();

  const float* Wb = Ws + n * 132 + c * 16;
  #pragma unroll 2
  for (int r = 0; r < 8; ++r) {
    const float* Wr = Wb + r * 1056;
    float s0 = 0.f, s1 = 0.f, wss = 0.f;
    #pragma unroll
    for (int j = 0; j < 4; ++j) {
      float4 w4 = *(const float4*)(Wr + 4 * j);
      s0 = fmaf(qa[j].x, w4.x, s0); s0 = fmaf(qa[j].y, w4.y, s0);
      s0 = fmaf(qa[j].z, w4.z, s0); s0 = fmaf(qa[j].w, w4.w, s0);
      s1 = fmaf(qb[j].x, w4.x, s1); s1 = fmaf(qb[j].y, w4.y, s1);
      s1 = fmaf(qb[j].z, w4.z, s1); s1 = fmaf(qb[j].w, w4.w, s1);
      wss = fmaf(w4.x, w4.x, wss); wss = fmaf(w4.y, w4.y, wss);
      wss = fmaf(w4.z, w4.z, wss); wss = fmaf(w4.w, w4.w, wss);
    }
    #pragma unroll
    for (int m = 1; m <= 4; m <<= 1) {
      s0  += __shfl_xor(s0, m, 64);
      s1  += __shfl_xor(s1, m, 64);
      wss += __shfl_xor(wss, m, 64);
    }
    const float iw  = 1.0f / fmaxf(sqrtf(wss), 1e-8f);
    const float cs0 = fmaxf(s0 * iq0 * iw, 0.f);
    const float cs1 = fmaxf(s1 * iq1 * iw, 0.f);
    float csv = (c == 0) ? cs0 : cs1;
    if (c < 2) Cs[(2 * wv + c) * 64 + r * 8 + n] = csv;
  }

  const bool m2 = lane & 1,  m3 = lane & 2,  m4 = lane & 4;
  const bool m5 = lane & 8,  m6 = lane & 16, m7 = lane & 32;
  float* outL = out + lane * 4;
  #pragma unroll 4
  for (int pi = 0; pi < 16; ++pi) {
    const int p = wv * 16 + pi;
    float4 va = *(const float4*)(Cs + p * 8);
    float4 vb = *(const float4*)(Cs + p * 8 + 4);
    float t2 = m2 ? 1.f - va.z : va.z;
    float t3 = m3 ? 1.f - va.w : va.w;
    float t4 = m4 ? 1.f - vb.x : vb.x;
    float t5 = m5 ? 1.f - vb.y : vb.y;
    float t6 = m6 ? 1.f - vb.z : vb.z;
    float t7 = m7 ? 1.f - vb.w : vb.w;
    float base = ((t2 * t3) * (t4 * t5)) * (t6 * t7);
    float c0 = va.x, c1 = va.y;
    float4 o;
    o.x = base * (c0 * c1);
    o.y = base * ((1.f - c0) * c1);
    o.z = base * (c0 * (1.f - c1));
    o.w = base * ((1.f - c0) * (1.f - c1));
    *(float4*)(outL +
        ((size_t)(bs + (p >> 3)) * NROWS + (rs + (p & 7))) * NCOMBO) = o;
  }
}

// ---------------------------------------------------------------------------
extern "C" void kernel_launch(void* const* d_in, const int* in_sizes, int n_in,
                              void* d_out, int out_size, void* d_ws, size_t ws_size,
                              hipStream_t stream) {
  const float* query  = (const float*)d_in[0];   // [512][1024]
  const float* weight = (const float*)d_in[1];   // [256][1024]
  float* out = (float*)d_out;                    // [512][256][256]

  const size_t cs_bytes = (size_t)BATCH * NROWS * NVECS * sizeof(float); // 4MB
  if (d_ws != nullptr && ws_size >= cs_bytes) {
    float* cs = (float*)d_ws;
    hipLaunchKernelGGL(cos_kernel, dim3(64, 32), dim3(256), 0, stream,
                       query, weight, cs);
    hipLaunchKernelGGL(expand_kernel, dim3(2048), dim3(256), 0, stream,
                       cs, out);
  } else {
    hipLaunchKernelGGL(fused_kernel, dim3(64, 32), dim3(256), 0, stream,
                       query, weight, out);
  }
}

// Round 6
// 154.198 us; speedup vs baseline: 1.0357x; 1.0357x over previous
//
#include <hip/hip_runtime.h>
#include <math.h>

#define BATCH  512
#define NROWS  256
#define NVECS  8
#define VSIZE  128
#define DIM    1024   // NVECS*VSIZE
#define NCOMBO 256

// ---------------------------------------------------------------------------
// R6: two-kernel split, A rebuilt on the PROVEN R4 structure.
//
// R5's split regressed because cos_kernel read W from global with a
// stride-64B per-lane pattern = 64-line address divergence per instruction
// (the exact trap documented in the original kernel's comments). R6's A is
// R4's verified front half unchanged: coalesced W->LDS staging (padded
// 132-float segments), hoisted per-sub-vector w-norms iwS[64] (R4-verified),
// 2-var butterfly r-loop -- but ending in a 4 MB cs[] write to d_ws instead
// of the expand phase. B (expand) is unchanged from R5: fill-shaped pure
// streaming, zero LDS / cross-lane / barriers, 1 KB contiguous store per
// wave-instruction, 16 KB contiguous per wave.
//
// Model: A ~= 18-22us (DS floor ~11us/CU + bubbles), B ~= 24-28us (128 MiB
// at ~5.5 TB/s), vs fused 63us where stores, DS pipe, and butterfly latency
// chains all serialize within the same waves.
// ---------------------------------------------------------------------------

__global__ __launch_bounds__(256) void cos_kernel(
    const float* __restrict__ q, const float* __restrict__ w,
    float* __restrict__ cs) {
  __shared__ __align__(16) float Ws[8 * 1056];   // 33 KB: 8 rows, 8x(128+4)
  __shared__ float iwS[64];                      // [r][n] inverse sub-norms
  const int t    = threadIdx.x;
  const int wv   = t >> 6, lane = t & 63;
  const int bs   = blockIdx.x * 8, rs = blockIdx.y * 8;
  const int n    = lane >> 3, c = lane & 7;
  const int koff = n * VSIZE + c * 16;
  const int b0   = bs + 2 * wv;

  // stage W tile (8 x 1024 floats): consecutive threads -> consecutive 16B
  #pragma unroll
  for (int i = 0; i < 8; ++i) {
    int f = i * 256 + t;        // float4 index 0..2047
    int g = f << 2;             // element index
    int row = g >> 10, e = g & 1023;
    float4 v = *(const float4*)(w + (size_t)(rs + row) * DIM + e);
    *(float4*)(Ws + row * 1056 + (e >> 7) * 132 + (e & 127)) = v;
  }

  // w sub-norms (R4-verified): wave wv handles rows 2wv, 2wv+1.
  #pragma unroll
  for (int h = 0; h < 2; ++h) {
    const int row = 2 * wv + h;
    const float* Wr = w + (size_t)(rs + row) * DIM + koff;
    float ss = 0.f;
    #pragma unroll
    for (int jj = 0; jj < 4; ++jj) {
      float4 v = *(const float4*)(Wr + 4 * jj);
      ss = fmaf(v.x, v.x, ss); ss = fmaf(v.y, v.y, ss);
      ss = fmaf(v.z, v.z, ss); ss = fmaf(v.w, v.w, ss);
    }
    #pragma unroll
    for (int m = 1; m <= 4; m <<= 1) ss += __shfl_xor(ss, m, 64);
    if (c == 0) iwS[row * 8 + n] = 1.0f / fmaxf(sqrtf(ss), 1e-8f);
  }

  // Q rows -> registers; per-chunk inverse norms via 3-step group butterfly.
  float4 qa[4], qb[4];
  float qs0 = 0.f, qs1 = 0.f;
  {
    const float* Q0 = q + (size_t)b0 * DIM + koff;
    #pragma unroll
    for (int j = 0; j < 4; ++j) {
      qa[j] = *(const float4*)(Q0 + 4 * j);
      qb[j] = *(const float4*)(Q0 + DIM + 4 * j);
      qs0 = fmaf(qa[j].x, qa[j].x, qs0); qs0 = fmaf(qa[j].y, qa[j].y, qs0);
      qs0 = fmaf(qa[j].z, qa[j].z, qs0); qs0 = fmaf(qa[j].w, qa[j].w, qs0);
      qs1 = fmaf(qb[j].x, qb[j].x, qs1); qs1 = fmaf(qb[j].y, qb[j].y, qs1);
      qs1 = fmaf(qb[j].z, qb[j].z, qs1); qs1 = fmaf(qb[j].w, qb[j].w, qs1);
    }
  }
  #pragma unroll
  for (int m = 1; m <= 4; m <<= 1) {
    qs0 += __shfl_xor(qs0, m, 64);
    qs1 += __shfl_xor(qs1, m, 64);
  }
  const float iq0 = 1.0f / fmaxf(sqrtf(qs0), 1e-8f);
  const float iq1 = 1.0f / fmaxf(sqrtf(qs1), 1e-8f);

  __syncthreads();   // covers Ws staging AND iwS

  // dots -> cs (global, 4 MB total; 2 scattered 4B stores per group per r)
  const float* Wb = Ws + n * 132 + c * 16;
  #pragma unroll 2
  for (int r = 0; r < 8; ++r) {
    const float* Wr = Wb + r * 1056;
    float s0 = 0.f, s1 = 0.f;
    #pragma unroll
    for (int j = 0; j < 4; ++j) {
      float4 w4 = *(const float4*)(Wr + 4 * j);
      s0 = fmaf(qa[j].x, w4.x, s0); s0 = fmaf(qa[j].y, w4.y, s0);
      s0 = fmaf(qa[j].z, w4.z, s0); s0 = fmaf(qa[j].w, w4.w, s0);
      s1 = fmaf(qb[j].x, w4.x, s1); s1 = fmaf(qb[j].y, w4.y, s1);
      s1 = fmaf(qb[j].z, w4.z, s1); s1 = fmaf(qb[j].w, w4.w, s1);
    }
    #pragma unroll
    for (int m = 1; m <= 4; m <<= 1) {
      s0 += __shfl_xor(s0, m, 64);
      s1 += __shfl_xor(s1, m, 64);
    }
    const float iw  = iwS[r * 8 + n];  // per-group broadcast, conflict-free
    const float cs0 = fmaxf(s0 * iq0 * iw, 0.f);
    const float cs1 = fmaxf(s1 * iq1 * iw, 0.f);
    if (c < 2) {
      float csv = (c == 0) ? cs0 : cs1;
      cs[((size_t)(b0 + c) * NROWS + (rs + r)) * 8 + n] = csv;
    }
  }
}

__global__ __launch_bounds__(256) void expand_kernel(
    const float* __restrict__ cs, float* __restrict__ out) {
  const int t    = threadIdx.x;
  const int wv   = t >> 6, lane = t & 63;
  const bool m2 = lane & 1,  m3 = lane & 2,  m4 = lane & 4;
  const bool m5 = lane & 8,  m6 = lane & 16, m7 = lane & 32;
  const int wbase = (blockIdx.x * 4 + wv) * 16;   // pair index base
  float* outL = out + lane * 4;
  #pragma unroll 4
  for (int it = 0; it < 16; ++it) {
    // p is wave-uniform; readfirstlane tells the compiler so (scalar loads).
    const int p = __builtin_amdgcn_readfirstlane(wbase + it);
    const float* cp = cs + ((size_t)p << 3);
    float4 va = *(const float4*)(cp);       // cs[0..3]
    float4 vb = *(const float4*)(cp + 4);   // cs[4..7]
    float t2 = m2 ? 1.f - va.z : va.z;
    float t3 = m3 ? 1.f - va.w : va.w;
    float t4 = m4 ? 1.f - vb.x : vb.x;
    float t5 = m5 ? 1.f - vb.y : vb.y;
    float t6 = m6 ? 1.f - vb.z : vb.z;
    float t7 = m7 ? 1.f - vb.w : vb.w;
    float base = ((t2 * t3) * (t4 * t5)) * (t6 * t7);
    float c0 = va.x, c1 = va.y;
    float4 o;
    o.x = base * (c0 * c1);
    o.y = base * ((1.f - c0) * c1);
    o.z = base * (c0 * (1.f - c1));
    o.w = base * ((1.f - c0) * (1.f - c1));
    *(float4*)(outL + ((size_t)p << 8)) = o;   // p*256 floats, 1KB/wave
  }
}

// ---------------------------------------------------------------------------
// Fallback (known-good R1 fused kernel, 145us) if the workspace is too small.
// ---------------------------------------------------------------------------
__global__ __launch_bounds__(256) void fused_kernel(
    const float* __restrict__ q, const float* __restrict__ w,
    float* __restrict__ out) {
  __shared__ __align__(16) float Ws[8 * 1056];
  __shared__ __align__(16) float Cs[8 * 64];
  const int t    = threadIdx.x;
  const int wv   = t >> 6, lane = t & 63;
  const int bs   = blockIdx.x * 8, rs = blockIdx.y * 8;
  const int n    = lane >> 3, c = lane & 7;
  const int koff = n * VSIZE + c * 16;
  const int b0   = bs + 2 * wv;

  #pragma unroll
  for (int i = 0; i < 8; ++i) {
    int f = i * 256 + t;
    int g = f << 2;
    int row = g >> 10, e = g & 1023;
    float4 v = *(const float4*)(w + (size_t)(rs + row) * DIM + e);
    *(float4*)(Ws + row * 1056 + (e >> 7) * 132 + (e & 127)) = v;
  }

  float4 qa[4], qb[4];
  float qs0 = 0.f, qs1 = 0.f;
  {
    const float* Q0 = q + (size_t)b0 * DIM + koff;
    #pragma unroll
    for (int j = 0; j < 4; ++j) {
      qa[j] = *(const float4*)(Q0 + 4 * j);
      qb[j] = *(const float4*)(Q0 + DIM + 4 * j);
      qs0 = fmaf(qa[j].x, qa[j].x, qs0); qs0 = fmaf(qa[j].y, qa[j].y, qs0);
      qs0 = fmaf(qa[j].z, qa[j].z, qs0); qs0 = fmaf(qa[j].w, qa[j].w, qs0);
      qs1 = fmaf(qb[j].x, qb[j].x, qs1); qs1 = fmaf(qb[j].y, qb[j].y, qs1);
      qs1 = fmaf(qb[j].z, qb[j].z, qs1); qs1 = fmaf(qb[j].w, qb[j].w, qs1);
    }
  }
  #pragma unroll
  for (int m = 1; m <= 4; m <<= 1) {
    qs0 += __shfl_xor(qs0, m, 64);
    qs1 += __shfl_xor(qs1, m, 64);
  }
  const float iq0 = 1.0f / fmaxf(sqrtf(qs0), 1e-8f);
  const float iq1 = 1.0f / fmaxf(sqrtf(qs1), 1e-8f);

  __syncthreads();

  const float* Wb = Ws + n * 132 + c * 16;
  #pragma unroll 2
  for (int r = 0; r < 8; ++r) {
    const float* Wr = Wb + r * 1056;
    float s0 = 0.f, s1 = 0.f, wss = 0.f;
    #pragma unroll
    for (int j = 0; j < 4; ++j) {
      float4 w4 = *(const float4*)(Wr + 4 * j);
      s0 = fmaf(qa[j].x, w4.x, s0); s0 = fmaf(qa[j].y, w4.y, s0);
      s0 = fmaf(qa[j].z, w4.z, s0); s0 = fmaf(qa[j].w, w4.w, s0);
      s1 = fmaf(qb[j].x, w4.x, s1); s1 = fmaf(qb[j].y, w4.y, s1);
      s1 = fmaf(qb[j].z, w4.z, s1); s1 = fmaf(qb[j].w, w4.w, s1);
      wss = fmaf(w4.x, w4.x, wss); wss = fmaf(w4.y, w4.y, wss);
      wss = fmaf(w4.z, w4.z, wss); wss = fmaf(w4.w, w4.w, wss);
    }
    #pragma unroll
    for (int m = 1; m <= 4; m <<= 1) {
      s0  += __shfl_xor(s0, m, 64);
      s1  += __shfl_xor(s1, m, 64);
      wss += __shfl_xor(wss, m, 64);
    }
    const float iw  = 1.0f / fmaxf(sqrtf(wss), 1e-8f);
    const float cs0 = fmaxf(s0 * iq0 * iw, 0.f);
    const float cs1 = fmaxf(s1 * iq1 * iw, 0.f);
    float csv = (c == 0) ? cs0 : cs1;
    if (c < 2) Cs[(2 * wv + c) * 64 + r * 8 + n] = csv;
  }

  const bool m2 = lane & 1,  m3 = lane & 2,  m4 = lane & 4;
  const bool m5 = lane & 8,  m6 = lane & 16, m7 = lane & 32;
  float* outL = out + lane * 4;
  #pragma unroll 4
  for (int pi = 0; pi < 16; ++pi) {
    const int p = wv * 16 + pi;
    float4 va = *(const float4*)(Cs + p * 8);
    float4 vb = *(const float4*)(Cs + p * 8 + 4);
    float t2 = m2 ? 1.f - va.z : va.z;
    float t3 = m3 ? 1.f - va.w : va.w;
    float t4 = m4 ? 1.f - vb.x : vb.x;
    float t5 = m5 ? 1.f - vb.y : vb.y;
    float t6 = m6 ? 1.f - vb.z : vb.z;
    float t7 = m7 ? 1.f - vb.w : vb.w;
    float base = ((t2 * t3) * (t4 * t5)) * (t6 * t7);
    float c0 = va.x, c1 = va.y;
    float4 o;
    o.x = base * (c0 * c1);
    o.y = base * ((1.f - c0) * c1);
    o.z = base * (c0 * (1.f - c1));
    o.w = base * ((1.f - c0) * (1.f - c1));
    *(float4*)(outL +
        ((size_t)(bs + (p >> 3)) * NROWS + (rs + (p & 7))) * NCOMBO) = o;
  }
}

// ---------------------------------------------------------------------------
extern "C" void kernel_launch(void* const* d_in, const int* in_sizes, int n_in,
                              void* d_out, int out_size, void* d_ws, size_t ws_size,
                              hipStream_t stream) {
  const float* query  = (const float*)d_in[0];   // [512][1024]
  const float* weight = (const float*)d_in[1];   // [256][1024]
  float* out = (float*)d_out;                    // [512][256][256]

  const size_t cs_bytes = (size_t)BATCH * NROWS * NVECS * sizeof(float); // 4MB
  if (d_ws != nullptr && ws_size >= cs_bytes) {
    float* cs = (float*)d_ws;
    hipLaunchKernelGGL(cos_kernel, dim3(64, 32), dim3(256), 0, stream,
                       query, weight, cs);
    hipLaunchKernelGGL(expand_kernel, dim3(2048), dim3(256), 0, stream,
                       cs, out);
  } else {
    hipLaunchKernelGGL(fused_kernel, dim3(64, 32), dim3(256), 0, stream,
                       query, weight, out);
  }
}

// Round 7
// 140.568 us; speedup vs baseline: 1.1362x; 1.0970x over previous
//
#include <hip/hip_runtime.h>
#include <math.h>

#define BATCH  512
#define NROWS  256
#define NVECS  8
#define VSIZE  128
#define DIM    1024   // NVECS*VSIZE
#define NCOMBO 256

// ---------------------------------------------------------------------------
// R7: proven R0 fused kernel with DS-pipe butterflies replaced by DPP adds.
//
// R6's split isolated the cost: dot phase ~45us of the 63us region; stores
// overlap nearly free. The dot phase's tax is the __shfl_xor butterflies:
// they lower to ds_swizzle/ds_bpermute (per-CU DS pipe, ~120cy latency,
// 3-deep dependent chain per r). R7 does the 8-lane-group reduction with
// DPP-modified v_add_f32 instead: xor1 = quad_perm[1,0,3,2] (0xB1),
// xor2 = quad_perm[2,3,0,1] (0x4E), cross-quad = row_half_mirror (0x141).
// Pure VALU: ~8cy dependent latency, zero DS occupancy. Explains-all-nulls
// check: R1 moved stores (not DS), R2 added waves (DS pipe is per-CU),
// R4 cut FMAs (not the chain). Everything else is byte-identical to the
// 144.9us baseline.
// ---------------------------------------------------------------------------

// sum over each 8-lane group (lanes l&~7 .. l|7), result in all 8 lanes
__device__ __forceinline__ float dpp8_sum(float x) {
  int v;
  v = __builtin_amdgcn_update_dpp(0, __float_as_int(x), 0xB1, 0xF, 0xF, true);
  x += __int_as_float(v);                       // + lane^1  (quad_perm 1,0,3,2)
  v = __builtin_amdgcn_update_dpp(0, __float_as_int(x), 0x4E, 0xF, 0xF, true);
  x += __int_as_float(v);                       // + lane^2  (quad_perm 2,3,0,1)
  v = __builtin_amdgcn_update_dpp(0, __float_as_int(x), 0x141, 0xF, 0xF, true);
  x += __int_as_float(v);                       // + other quad (row_half_mirror)
  return x;
}

__global__ __launch_bounds__(256) void fused_kernel(
    const float* __restrict__ q, const float* __restrict__ w,
    float* __restrict__ out) {
  __shared__ __align__(16) float Ws[8 * 1056];  // 33 KB: 8 rows, 8x(128+4)
  const int t    = threadIdx.x;
  const int wv   = t >> 6, lane = t & 63;
  const int bs   = blockIdx.x * 8, rs = blockIdx.y * 8;
  const int n    = lane >> 3, c = lane & 7;
  const int koff = n * VSIZE + c * 16;
  const int b0   = bs + 2 * wv;

  // stage W tile (8 x 1024 floats): consecutive threads -> consecutive 16B
  #pragma unroll
  for (int i = 0; i < 8; ++i) {
    int f = i * 256 + t;        // float4 index 0..2047
    int g = f << 2;             // element index
    int row = g >> 10, e = g & 1023;
    float4 v = *(const float4*)(w + (size_t)(rs + row) * DIM + e);
    *(float4*)(Ws + row * 1056 + (e >> 7) * 132 + (e & 127)) = v;
  }

  // Q rows -> registers; inline sub-vector inverse norms via DPP reduce.
  float4 qa[4], qb[4];
  float qs0 = 0.f, qs1 = 0.f;
  {
    const float* Q0 = q + (size_t)b0 * DIM + koff;
    #pragma unroll
    for (int j = 0; j < 4; ++j) {
      qa[j] = *(const float4*)(Q0 + 4 * j);
      qb[j] = *(const float4*)(Q0 + DIM + 4 * j);
      qs0 = fmaf(qa[j].x, qa[j].x, qs0); qs0 = fmaf(qa[j].y, qa[j].y, qs0);
      qs0 = fmaf(qa[j].z, qa[j].z, qs0); qs0 = fmaf(qa[j].w, qa[j].w, qs0);
      qs1 = fmaf(qb[j].x, qb[j].x, qs1); qs1 = fmaf(qb[j].y, qb[j].y, qs1);
      qs1 = fmaf(qb[j].z, qb[j].z, qs1); qs1 = fmaf(qb[j].w, qb[j].w, qs1);
    }
  }
  qs0 = dpp8_sum(qs0);
  qs1 = dpp8_sum(qs1);
  const float iq0 = 1.0f / fmaxf(sqrtf(qs0), 1e-8f);
  const float iq1 = 1.0f / fmaxf(sqrtf(qs1), 1e-8f);

  __syncthreads();

  const float* Wb = Ws + n * 132 + c * 16;
  float* out0 = out + ((size_t)b0 * NROWS + rs) * NCOMBO + lane * 4;

  #pragma unroll 2
  for (int r = 0; r < 8; ++r) {
    // --- dots + w-norm for row rs+r (W from LDS) ---
    const float* Wr = Wb + r * 1056;
    float s0 = 0.f, s1 = 0.f, wss = 0.f;
    #pragma unroll
    for (int j = 0; j < 4; ++j) {
      float4 w4 = *(const float4*)(Wr + 4 * j);
      s0 = fmaf(qa[j].x, w4.x, s0); s0 = fmaf(qa[j].y, w4.y, s0);
      s0 = fmaf(qa[j].z, w4.z, s0); s0 = fmaf(qa[j].w, w4.w, s0);
      s1 = fmaf(qb[j].x, w4.x, s1); s1 = fmaf(qb[j].y, w4.y, s1);
      s1 = fmaf(qb[j].z, w4.z, s1); s1 = fmaf(qb[j].w, w4.w, s1);
      wss = fmaf(w4.x, w4.x, wss); wss = fmaf(w4.y, w4.y, wss);
      wss = fmaf(w4.z, w4.z, wss); wss = fmaf(w4.w, w4.w, wss);
    }
    s0  = dpp8_sum(s0);
    s1  = dpp8_sum(s1);
    wss = dpp8_sum(wss);
    const float iw  = 1.0f / fmaxf(sqrtf(wss), 1e-8f);
    const float cs0 = fmaxf(s0 * iq0 * iw, 0.f);
    const float cs1 = fmaxf(s1 * iq1 * iw, 0.f);

    // broadcast cs[n] from lane 8n to all lanes (uniform index -> readlane)
    float v0[8], v1[8];
    #pragma unroll
    for (int j = 0; j < 8; ++j) {
      v0[j] = __shfl(cs0, j * 8, 64);
      v1[j] = __shfl(cs1, j * 8, 64);
    }

    // --- expand + store both b-rows for this r (stores spread over loop) ---
    #pragma unroll
    for (int pp = 0; pp < 2; ++pp) {
      const float* v = pp ? v1 : v0;
      float t2 = (lane & 1)  ? 1.f - v[2] : v[2];
      float t3 = (lane & 2)  ? 1.f - v[3] : v[3];
      float t4 = (lane & 4)  ? 1.f - v[4] : v[4];
      float t5 = (lane & 8)  ? 1.f - v[5] : v[5];
      float t6 = (lane & 16) ? 1.f - v[6] : v[6];
      float t7 = (lane & 32) ? 1.f - v[7] : v[7];
      float base = ((t2 * t3) * (t4 * t5)) * (t6 * t7);
      float c0 = v[0], c1 = v[1];
      float4 o;
      o.x = base * (c0 * c1);
      o.y = base * ((1.f - c0) * c1);
      o.z = base * (c0 * (1.f - c1));
      o.w = base * ((1.f - c0) * (1.f - c1));
      *(float4*)(out0 + ((size_t)pp * NROWS + r) * NCOMBO) = o;
    }
  }
}

// ---------------------------------------------------------------------------
extern "C" void kernel_launch(void* const* d_in, const int* in_sizes, int n_in,
                              void* d_out, int out_size, void* d_ws, size_t ws_size,
                              hipStream_t stream) {
  const float* query  = (const float*)d_in[0];   // [512][1024]
  const float* weight = (const float*)d_in[1];   // [256][1024]
  float* out = (float*)d_out;                    // [512][256][256]
  (void)d_ws; (void)ws_size;

  hipLaunchKernelGGL(fused_kernel, dim3(64, 32), dim3(256), 0, stream,
                     query, weight, out);
}